// Round 2
// baseline (156.321 us; speedup 1.0000x reference)
//
#include <hip/hip_runtime.h>
#include <stdint.h>

#define NB 8
#define NN 1024
#define NF 64
#define NT 12
#define NK 3
#define NO 64
#define NQ 768      // O*T
#define KKC 3072    // NK*NN contraction

typedef __attribute__((ext_vector_type(8))) short bf16x8;
typedef __attribute__((ext_vector_type(4))) float f32x4;

typedef const unsigned int __attribute__((address_space(1)))* gas1_t;
typedef unsigned int __attribute__((address_space(3)))* las3_t;

__device__ __forceinline__ void gload_lds16(const void* g, void* l) {
  __builtin_amdgcn_global_load_lds((gas1_t)g, (las3_t)l, 16, 0, 0);
}

__device__ __forceinline__ unsigned short f2bf(float f) {
  union { float f; unsigned int u; } v; v.f = f;
  unsigned int u = v.u;
  unsigned int r = (u + 0x7FFFu + ((u >> 16) & 1u)) >> 16;
  return (unsigned short)r;
}

// ---------------------------------------------------------------------------
// K0: thetaT[k][o][f] = bf16(theta[k][f][o])          (3*64*64 elements)
// ---------------------------------------------------------------------------
__global__ void k0_thetaT(const float* __restrict__ theta, unsigned short* __restrict__ thT) {
  int i = blockIdx.x * 256 + threadIdx.x;
  if (i >= NK * NO * NF) return;
  int f = i & 63, o = (i >> 6) & 63, k = i >> 12;
  thT[i] = f2bf(theta[(k * NF + f) * NO + o]);
}

// ---------------------------------------------------------------------------
// K1: A2[b][n][k*1024+m] = bf16(cheb[k][m][n]*att[b][m][n])
// 64x64 tiles via LDS transpose; k-loop inside reuses the att tile.
// grid: (n-tile 16, m-tile 16, b 8), 256 threads
// ---------------------------------------------------------------------------
__global__ __launch_bounds__(256) void k1_A2(const float* __restrict__ cheb,
                                             const float* __restrict__ att,
                                             unsigned short* __restrict__ A2) {
  __shared__ float att_s[64][65];
  __shared__ float cheb_s[64][65];
  const int n0 = blockIdx.x * 64;
  const int m0 = blockIdx.y * 64;
  const int b  = blockIdx.z;
  const int tid = threadIdx.x;
  const int r4 = tid >> 4;        // 0..15
  const int c  = tid & 15;        // 0..15 (float4 column)

#pragma unroll
  for (int p = 0; p < 4; ++p) {
    int r = r4 + p * 16;
    const float4 v = *(const float4*)(att + ((size_t)(b * NN + m0 + r)) * NN + n0 + c * 4);
    att_s[r][c * 4 + 0] = v.x; att_s[r][c * 4 + 1] = v.y;
    att_s[r][c * 4 + 2] = v.z; att_s[r][c * 4 + 3] = v.w;
  }
  for (int k = 0; k < NK; ++k) {
#pragma unroll
    for (int p = 0; p < 4; ++p) {
      int r = r4 + p * 16;
      const float4 v = *(const float4*)(cheb + ((size_t)(k * NN + m0 + r)) * NN + n0 + c * 4);
      cheb_s[r][c * 4 + 0] = v.x; cheb_s[r][c * 4 + 1] = v.y;
      cheb_s[r][c * 4 + 2] = v.z; cheb_s[r][c * 4 + 3] = v.w;
    }
    __syncthreads();
#pragma unroll
    for (int p = 0; p < 8; ++p) {
      int e  = p * 256 + tid;     // 0..2047
      int jn = e >> 5;            // n within tile, 0..63
      int q  = e & 31;            // m-pair, 0..31
      float f0 = att_s[2 * q][jn]     * cheb_s[2 * q][jn];
      float f1 = att_s[2 * q + 1][jn] * cheb_s[2 * q + 1][jn];
      unsigned int pk = (unsigned int)f2bf(f0) | ((unsigned int)f2bf(f1) << 16);
      size_t el = ((size_t)(b * NN + n0 + jn)) * KKC + k * NN + m0 + 2 * q;
      *(unsigned int*)(A2 + el) = pk;
    }
    __syncthreads();
  }
}

// ---------------------------------------------------------------------------
// K2: xT[b][t][m][f] = bf16(x[b][m][f][t])
// LDS-transpose version: fully contiguous global reads (x is t-innermost, so
// per-(m,f-pair) we grab 24 consecutive floats), pack bf16 into LDS [t][m][fp],
// write out coalesced uint2. Block = (m-chunk of 16, b). 98KB read/block.
// ---------------------------------------------------------------------------
__global__ __launch_bounds__(256) void k2_xT(const float* __restrict__ x,
                                             unsigned short* __restrict__ xT) {
  __shared__ unsigned int lds[12][16][32];   // [t][m_loc][f-pair]
  const int m0 = blockIdx.x * 16;
  const int b  = blockIdx.y;
  const int tid = threadIdx.x;
  const float* xb = x + ((size_t)(b * NN + m0)) * (NF * NT);

#pragma unroll
  for (int u0 = 0; u0 < 2; ++u0) {
    const int u  = u0 * 256 + tid;       // 0..511
    const int ml = u >> 5;               // 0..15
    const int fp = u & 31;               // f-pair 0..31
    const float* src = xb + ((size_t)ml * NF + fp * 2) * NT;  // 24 consecutive floats
    float v[24];
#pragma unroll
    for (int i = 0; i < 6; ++i)
      *(float4*)(v + i * 4) = *(const float4*)(src + i * 4);
#pragma unroll
    for (int t = 0; t < 12; ++t) {
      unsigned int pk = (unsigned int)f2bf(v[t]) | ((unsigned int)f2bf(v[t + 12]) << 16);
      lds[t][ml][fp] = pk;
    }
  }
  __syncthreads();

#pragma unroll
  for (int it = 0; it < 12; ++it) {
    const int g = it * 256 + tid;        // uint2 index, 3072 total
    const int t = g >> 8;                // 256 uint2 per t
    const int r = g & 255;
    const int m = r >> 4;
    const int f4 = r & 15;               // 4-bf16 unit
    uint2 u = *(const uint2*)&lds[t][m][2 * f4];
    size_t el = (((size_t)(b * NT + t) * NN) + m0 + m) * NF + f4 * 4;
    *(uint2*)(void*)(xT + el) = u;
  }
}

// ---------------------------------------------------------------------------
// K3: Y2t[b][o*12+t][k*1024+m] = sum_f xT[b][t][m][f] * thT[k][o][f]
// ---------------------------------------------------------------------------
__global__ __launch_bounds__(256) void k3_Y(const unsigned short* __restrict__ xT,
                                            const unsigned short* __restrict__ thT,
                                            unsigned short* __restrict__ Y) {
  const int mc = blockIdx.x;
  const int tk = blockIdx.y;
  const int b  = blockIdx.z;
  const int t = tk / 3, k = tk % 3;
  const int tid = threadIdx.x;
  const int w = tid >> 6, l = tid & 63;
  const int lrow = l & 15, lk = l >> 4;
  const int mbase = mc * 256 + w * 64;

  const unsigned short* xbase = xT + ((size_t)(b * NT + t)) * NN * NF;
  const unsigned short* tbase = thT + (size_t)k * NO * NF;

  f32x4 acc[4][4] = {};
#pragma unroll
  for (int ks = 0; ks < 2; ++ks) {
    const int fo = ks * 32 + lk * 8;
    bf16x8 a[4], bb[4];
#pragma unroll
    for (int mi = 0; mi < 4; ++mi)
      a[mi] = *(const bf16x8*)(xbase + (size_t)(mbase + mi * 16 + lrow) * NF + fo);
#pragma unroll
    for (int oj = 0; oj < 4; ++oj)
      bb[oj] = *(const bf16x8*)(tbase + (size_t)(oj * 16 + lrow) * NF + fo);
#pragma unroll
    for (int mi = 0; mi < 4; ++mi)
#pragma unroll
      for (int oj = 0; oj < 4; ++oj)
        acc[mi][oj] = __builtin_amdgcn_mfma_f32_16x16x32_bf16(a[mi], bb[oj], acc[mi][oj], 0, 0, 0);
  }
#pragma unroll
  for (int mi = 0; mi < 4; ++mi) {
#pragma unroll
    for (int oj = 0; oj < 4; ++oj) {
      const int o  = oj * 16 + lrow;
      const int mg = mbase + mi * 16 + lk * 4;
      uint2 u;
      u.x = (unsigned int)f2bf(acc[mi][oj][0]) | ((unsigned int)f2bf(acc[mi][oj][1]) << 16);
      u.y = (unsigned int)f2bf(acc[mi][oj][2]) | ((unsigned int)f2bf(acc[mi][oj][3]) << 16);
      size_t el = ((size_t)(b * NQ + o * NT + t)) * KKC + k * NN + mg;
      *(uint2*)(void*)(Y + el) = u;
    }
  }
}

// ---------------------------------------------------------------------------
// K4: partial[b][n][q] += A2[b](n, ks-half of KKC) @ Y[b]^T  (no relu yet)
// Split-K x2: 768 blocks = exactly 3/CU (balance + 12 waves/CU occupancy).
// Accumulated via fp32 atomicAdd into out (2 addends -> order-independent).
// XCD-chunked bijective swizzle: 96 consecutive tiles per XCD.
// ---------------------------------------------------------------------------
__global__ __launch_bounds__(256) void k4_main(const unsigned short* __restrict__ A2,
                                               const unsigned short* __restrict__ Y,
                                               float* __restrict__ out) {
  __shared__ unsigned short Asl[128 * 64];
  __shared__ unsigned short Bsl[128 * 64];
  const int tid = threadIdx.x;
  const int w = tid >> 6, l = tid & 63;
  const int lrow = l & 15, lk = l >> 4;
  const int wm = w >> 1, wn = w & 1;

  // bijective XCD-chunk swizzle (768 % 8 == 0)
  const int lin = (blockIdx.x & 7) * 96 + (blockIdx.x >> 3);
  const int bks = lin / 48;            // 0..15 = (b, ks)
  const int rem = lin % 48;
  const int bn = rem / 6, bq = rem % 6;
  const int b = bks >> 1, ks = bks & 1;

  const unsigned short* Abase = A2 + ((size_t)(b * NN + bn * 128)) * KKC;
  const unsigned short* Bbase = Y  + ((size_t)(b * NQ + bq * 128)) * KKC;
  const int kb0 = ks * (KKC / 2);

  f32x4 acc[4][4] = {};

  for (int kt = 0; kt < KKC / 2 / 64; ++kt) {
    const int kb = kb0 + kt * 64;
#pragma unroll
    for (int i = 0; i < 4; ++i) {
      const int g   = (w * 4 + i) * 64 + l;
      const int r   = g >> 3;
      const int c16 = (g & 7) ^ (r & 7);          // inverse-swizzled source column
      gload_lds16(Abase + (size_t)r * KKC + kb + c16 * 8, Asl + (w * 4 + i) * 512);
      gload_lds16(Bbase + (size_t)r * KKC + kb + c16 * 8, Bsl + (w * 4 + i) * 512);
    }
    __syncthreads();
#pragma unroll
    for (int kss = 0; kss < 2; ++kss) {
      bf16x8 af[4], bfr[4];
#pragma unroll
      for (int mi = 0; mi < 4; ++mi) {
        const int row = wm * 64 + mi * 16 + lrow;
        const int sw = (row * 128 + kss * 64 + lk * 16) ^ ((row & 7) << 4);
        af[mi] = *(const bf16x8*)((const char*)Asl + sw);
      }
#pragma unroll
      for (int nj = 0; nj < 4; ++nj) {
        const int row = wn * 64 + nj * 16 + lrow;
        const int sw = (row * 128 + kss * 64 + lk * 16) ^ ((row & 7) << 4);
        bfr[nj] = *(const bf16x8*)((const char*)Bsl + sw);
      }
#pragma unroll
      for (int mi = 0; mi < 4; ++mi)
#pragma unroll
        for (int nj = 0; nj < 4; ++nj)
          acc[mi][nj] = __builtin_amdgcn_mfma_f32_16x16x32_bf16(af[mi], bfr[nj], acc[mi][nj], 0, 0, 0);
    }
    __syncthreads();
  }

  const int nb0 = bn * 128 + wm * 64;
  const int qb0 = bq * 128 + wn * 64;
#pragma unroll
  for (int mi = 0; mi < 4; ++mi) {
#pragma unroll
    for (int nj = 0; nj < 4; ++nj) {
      const int q = qb0 + nj * 16 + lrow;
#pragma unroll
      for (int j = 0; j < 4; ++j) {
        const int n = nb0 + mi * 16 + lk * 4 + j;
        atomicAdd(&out[((size_t)(b * NN + n)) * NQ + q], acc[mi][nj][j]);
      }
    }
  }
}

// ---------------------------------------------------------------------------
// K5: out = relu(out), in place, float4.
// ---------------------------------------------------------------------------
__global__ void k5_relu(float* __restrict__ out) {
  const int total4 = NB * NN * NQ / 4;           // 1,572,864
  float4* p = (float4*)out;
  for (int i = blockIdx.x * 256 + threadIdx.x; i < total4; i += 2048 * 256) {
    float4 v = p[i];
    v.x = fmaxf(v.x, 0.f); v.y = fmaxf(v.y, 0.f);
    v.z = fmaxf(v.z, 0.f); v.w = fmaxf(v.w, 0.f);
    p[i] = v;
  }
}

// ---------------------------------------------------------------------------
extern "C" void kernel_launch(void* const* d_in, const int* in_sizes, int n_in,
                              void* d_out, int out_size, void* d_ws, size_t ws_size,
                              hipStream_t stream) {
  const float* x     = (const float*)d_in[0];   // (B,N,F,T)
  const float* att   = (const float*)d_in[1];   // (B,N,N)
  const float* cheb  = (const float*)d_in[2];   // (K,N,N)
  const float* theta = (const float*)d_in[3];   // (K,F,O)
  float* out = (float*)d_out;

  char* ws = (char*)d_ws;
  unsigned short* A2  = (unsigned short*)(ws);                 // 50,331,648 B
  unsigned short* xT  = (unsigned short*)(ws + 50331648);      // 12,582,912 B
  unsigned short* Y   = (unsigned short*)(ws + 62914560);      // 37,748,736 B
  unsigned short* thT = (unsigned short*)(ws + 100663296);     //     24,576 B

  hipMemsetAsync(out, 0, sizeof(float) * NB * NN * NQ, stream);
  k0_thetaT<<<48, 256, 0, stream>>>(theta, thT);
  k1_A2<<<dim3(16, 16, 8), 256, 0, stream>>>(cheb, att, A2);
  k2_xT<<<dim3(64, 8), 256, 0, stream>>>(x, xT);
  k3_Y<<<dim3(4, 36, 8), 256, 0, stream>>>(xT, thT, Y);
  k4_main<<<768, 256, 0, stream>>>(A2, Y, out);
  k5_relu<<<2048, 256, 0, stream>>>(out);
}

// Round 3
// 103.000 us; speedup vs baseline: 1.5177x; 1.5177x over previous
//
#include <hip/hip_runtime.h>
#include <stdint.h>

#define NB 8
#define NN 1024
#define NF 64
#define NT 12
#define NK 3
#define NO 64
#define NQ 768      // O*T
#define KKC 3072    // NK*NN contraction

typedef __attribute__((ext_vector_type(8))) short bf16x8;
typedef __attribute__((ext_vector_type(4))) float f32x4;

typedef const unsigned int __attribute__((address_space(1)))* gas1_t;
typedef unsigned int __attribute__((address_space(3)))* las3_t;

__device__ __forceinline__ void gload_lds16(const void* g, void* l) {
  __builtin_amdgcn_global_load_lds((gas1_t)g, (las3_t)l, 16, 0, 0);
}

__device__ __forceinline__ unsigned short f2bf(float f) {
  union { float f; unsigned int u; } v; v.f = f;
  unsigned int u = v.u;
  unsigned int r = (u + 0x7FFFu + ((u >> 16) & 1u)) >> 16;
  return (unsigned short)r;
}

// ---------------------------------------------------------------------------
// K0: thetaT[k][o][f] = bf16(theta[k][f][o])
// ---------------------------------------------------------------------------
__global__ void k0_thetaT(const float* __restrict__ theta, unsigned short* __restrict__ thT) {
  int i = blockIdx.x * 256 + threadIdx.x;
  if (i >= NK * NO * NF) return;
  int f = i & 63, o = (i >> 6) & 63, k = i >> 12;
  thT[i] = f2bf(theta[(k * NF + f) * NO + o]);
}

// ---------------------------------------------------------------------------
// K1: A2[b][n][k*1024+m] = bf16(cheb[k][m][n]*att[b][m][n])
// ---------------------------------------------------------------------------
__global__ __launch_bounds__(256) void k1_A2(const float* __restrict__ cheb,
                                             const float* __restrict__ att,
                                             unsigned short* __restrict__ A2) {
  __shared__ float att_s[64][65];
  __shared__ float cheb_s[64][65];
  const int n0 = blockIdx.x * 64;
  const int m0 = blockIdx.y * 64;
  const int b  = blockIdx.z;
  const int tid = threadIdx.x;
  const int r4 = tid >> 4;
  const int c  = tid & 15;

#pragma unroll
  for (int p = 0; p < 4; ++p) {
    int r = r4 + p * 16;
    const float4 v = *(const float4*)(att + ((size_t)(b * NN + m0 + r)) * NN + n0 + c * 4);
    att_s[r][c * 4 + 0] = v.x; att_s[r][c * 4 + 1] = v.y;
    att_s[r][c * 4 + 2] = v.z; att_s[r][c * 4 + 3] = v.w;
  }
  for (int k = 0; k < NK; ++k) {
#pragma unroll
    for (int p = 0; p < 4; ++p) {
      int r = r4 + p * 16;
      const float4 v = *(const float4*)(cheb + ((size_t)(k * NN + m0 + r)) * NN + n0 + c * 4);
      cheb_s[r][c * 4 + 0] = v.x; cheb_s[r][c * 4 + 1] = v.y;
      cheb_s[r][c * 4 + 2] = v.z; cheb_s[r][c * 4 + 3] = v.w;
    }
    __syncthreads();
#pragma unroll
    for (int p = 0; p < 8; ++p) {
      int e  = p * 256 + tid;
      int jn = e >> 5;
      int q  = e & 31;
      float f0 = att_s[2 * q][jn]     * cheb_s[2 * q][jn];
      float f1 = att_s[2 * q + 1][jn] * cheb_s[2 * q + 1][jn];
      unsigned int pk = (unsigned int)f2bf(f0) | ((unsigned int)f2bf(f1) << 16);
      size_t el = ((size_t)(b * NN + n0 + jn)) * KKC + k * NN + m0 + 2 * q;
      *(unsigned int*)(A2 + el) = pk;
    }
    __syncthreads();
  }
}

// ---------------------------------------------------------------------------
// K2: xT[b][t][m][f] = bf16(x[b][m][f][t])  (LDS transpose, contiguous reads)
// ---------------------------------------------------------------------------
__global__ __launch_bounds__(256) void k2_xT(const float* __restrict__ x,
                                             unsigned short* __restrict__ xT) {
  __shared__ unsigned int lds[12][16][32];
  const int m0 = blockIdx.x * 16;
  const int b  = blockIdx.y;
  const int tid = threadIdx.x;
  const float* xb = x + ((size_t)(b * NN + m0)) * (NF * NT);

#pragma unroll
  for (int u0 = 0; u0 < 2; ++u0) {
    const int u  = u0 * 256 + tid;
    const int ml = u >> 5;
    const int fp = u & 31;
    const float* src = xb + ((size_t)ml * NF + fp * 2) * NT;
    float v[24];
#pragma unroll
    for (int i = 0; i < 6; ++i)
      *(float4*)(v + i * 4) = *(const float4*)(src + i * 4);
#pragma unroll
    for (int t = 0; t < 12; ++t) {
      unsigned int pk = (unsigned int)f2bf(v[t]) | ((unsigned int)f2bf(v[t + 12]) << 16);
      lds[t][ml][fp] = pk;
    }
  }
  __syncthreads();

#pragma unroll
  for (int it = 0; it < 12; ++it) {
    const int g = it * 256 + tid;
    const int t = g >> 8;
    const int r = g & 255;
    const int m = r >> 4;
    const int f4 = r & 15;
    uint2 u = *(const uint2*)&lds[t][m][2 * f4];
    size_t el = (((size_t)(b * NT + t) * NN) + m0 + m) * NF + f4 * 4;
    *(uint2*)(void*)(xT + el) = u;
  }
}

// ---------------------------------------------------------------------------
// K3: Y2t[b][o*12+t][k*1024+m] = sum_f xT[b][t][m][f] * thT[k][o][f]
// ---------------------------------------------------------------------------
__global__ __launch_bounds__(256) void k3_Y(const unsigned short* __restrict__ xT,
                                            const unsigned short* __restrict__ thT,
                                            unsigned short* __restrict__ Y) {
  const int mc = blockIdx.x;
  const int tk = blockIdx.y;
  const int b  = blockIdx.z;
  const int t = tk / 3, k = tk % 3;
  const int tid = threadIdx.x;
  const int w = tid >> 6, l = tid & 63;
  const int lrow = l & 15, lk = l >> 4;
  const int mbase = mc * 256 + w * 64;

  const unsigned short* xbase = xT + ((size_t)(b * NT + t)) * NN * NF;
  const unsigned short* tbase = thT + (size_t)k * NO * NF;

  f32x4 acc[4][4] = {};
#pragma unroll
  for (int ks = 0; ks < 2; ++ks) {
    const int fo = ks * 32 + lk * 8;
    bf16x8 a[4], bb[4];
#pragma unroll
    for (int mi = 0; mi < 4; ++mi)
      a[mi] = *(const bf16x8*)(xbase + (size_t)(mbase + mi * 16 + lrow) * NF + fo);
#pragma unroll
    for (int oj = 0; oj < 4; ++oj)
      bb[oj] = *(const bf16x8*)(tbase + (size_t)(oj * 16 + lrow) * NF + fo);
#pragma unroll
    for (int mi = 0; mi < 4; ++mi)
#pragma unroll
      for (int oj = 0; oj < 4; ++oj)
        acc[mi][oj] = __builtin_amdgcn_mfma_f32_16x16x32_bf16(a[mi], bb[oj], acc[mi][oj], 0, 0, 0);
  }
#pragma unroll
  for (int mi = 0; mi < 4; ++mi) {
#pragma unroll
    for (int oj = 0; oj < 4; ++oj) {
      const int o  = oj * 16 + lrow;
      const int mg = mbase + mi * 16 + lk * 4;
      uint2 u;
      u.x = (unsigned int)f2bf(acc[mi][oj][0]) | ((unsigned int)f2bf(acc[mi][oj][1]) << 16);
      u.y = (unsigned int)f2bf(acc[mi][oj][2]) | ((unsigned int)f2bf(acc[mi][oj][3]) << 16);
      size_t el = ((size_t)(b * NQ + o * NT + t)) * KKC + k * NN + mg;
      *(uint2*)(void*)(Y + el) = u;
    }
  }
}

// ---------------------------------------------------------------------------
// K4: out[b][n][q] = relu( A2[b] @ Y[b]^T ), 64x128 tile, BK=64.
// 768 blocks = exactly 3/CU (balance, 12 waves/CU). Full K, plain stores.
// XCD-chunk swizzle: 96 consecutive tiles (= one b) per XCD -> L2 working
// set A2[b](6MB)+Y[b](4.7MB). Both-sides XOR swizzle, bank-conflict-free.
// ---------------------------------------------------------------------------
__global__ __launch_bounds__(256) void k4_main(const unsigned short* __restrict__ A2,
                                               const unsigned short* __restrict__ Y,
                                               float* __restrict__ out) {
  __shared__ unsigned short Asl[64 * 64];    //  8 KB
  __shared__ unsigned short Bsl[128 * 64];   // 16 KB
  const int tid = threadIdx.x;
  const int w = tid >> 6, l = tid & 63;
  const int lrow = l & 15, lk = l >> 4;
  const int wm = w >> 1, wq = w & 1;         // 2x2 wave grid over 64x128

  // bijective XCD-chunk swizzle (768 % 8 == 0); 96 blocks = one b per XCD
  const int lin = (blockIdx.x & 7) * 96 + (blockIdx.x >> 3);
  const int b   = lin / 96;
  const int rem = lin % 96;
  const int bn  = rem / 6;                   // 0..15, 64-row m-tile
  const int bq  = rem % 6;                   // 0..5, 128-col q-tile

  const unsigned short* Abase = A2 + ((size_t)(b * NN + bn * 64)) * KKC;
  const unsigned short* Bbase = Y  + ((size_t)(b * NQ + bq * 128)) * KKC;

  f32x4 acc[2][4] = {};

  for (int kt = 0; kt < KKC / 64; ++kt) {
    const int kb = kt * 64;
    // stage A: 512 lane-loads (2/thread), rows 0..63
#pragma unroll
    for (int it = 0; it < 2; ++it) {
      const int idx = it * 256 + tid;
      const int r   = idx >> 3;
      const int c16 = (idx & 7) ^ (r & 7);
      gload_lds16(Abase + (size_t)r * KKC + kb + c16 * 8, Asl + (size_t)idx * 8);
    }
    // stage B: 1024 lane-loads (4/thread), rows 0..127
#pragma unroll
    for (int it = 0; it < 4; ++it) {
      const int idx = it * 256 + tid;
      const int r   = idx >> 3;
      const int c16 = (idx & 7) ^ (r & 7);
      gload_lds16(Bbase + (size_t)r * KKC + kb + c16 * 8, Bsl + (size_t)idx * 8);
    }
    __syncthreads();
#pragma unroll
    for (int kss = 0; kss < 2; ++kss) {
      bf16x8 af[2], bfr[4];
#pragma unroll
      for (int mi = 0; mi < 2; ++mi) {
        const int row = wm * 32 + mi * 16 + lrow;
        const int sw = (row * 128 + kss * 64 + lk * 16) ^ ((row & 7) << 4);
        af[mi] = *(const bf16x8*)((const char*)Asl + sw);
      }
#pragma unroll
      for (int nj = 0; nj < 4; ++nj) {
        const int row = wq * 64 + nj * 16 + lrow;
        const int sw = (row * 128 + kss * 64 + lk * 16) ^ ((row & 7) << 4);
        bfr[nj] = *(const bf16x8*)((const char*)Bsl + sw);
      }
#pragma unroll
      for (int mi = 0; mi < 2; ++mi)
#pragma unroll
        for (int nj = 0; nj < 4; ++nj)
          acc[mi][nj] = __builtin_amdgcn_mfma_f32_16x16x32_bf16(af[mi], bfr[nj], acc[mi][nj], 0, 0, 0);
    }
    __syncthreads();
  }

  const int nb0 = bn * 64 + wm * 32;
  const int qb0 = bq * 128 + wq * 64;
#pragma unroll
  for (int mi = 0; mi < 2; ++mi) {
#pragma unroll
    for (int nj = 0; nj < 4; ++nj) {
      const int q = qb0 + nj * 16 + lrow;
#pragma unroll
      for (int j = 0; j < 4; ++j) {
        const int n = nb0 + mi * 16 + lk * 4 + j;
        float v = acc[mi][nj][j];
        out[((size_t)(b * NN + n)) * NQ + q] = v > 0.f ? v : 0.f;
      }
    }
  }
}

// ---------------------------------------------------------------------------
extern "C" void kernel_launch(void* const* d_in, const int* in_sizes, int n_in,
                              void* d_out, int out_size, void* d_ws, size_t ws_size,
                              hipStream_t stream) {
  const float* x     = (const float*)d_in[0];   // (B,N,F,T)
  const float* att   = (const float*)d_in[1];   // (B,N,N)
  const float* cheb  = (const float*)d_in[2];   // (K,N,N)
  const float* theta = (const float*)d_in[3];   // (K,F,O)
  float* out = (float*)d_out;

  char* ws = (char*)d_ws;
  unsigned short* A2  = (unsigned short*)(ws);                 // 50,331,648 B
  unsigned short* xT  = (unsigned short*)(ws + 50331648);      // 12,582,912 B
  unsigned short* Y   = (unsigned short*)(ws + 62914560);      // 37,748,736 B
  unsigned short* thT = (unsigned short*)(ws + 100663296);     //     24,576 B

  k0_thetaT<<<48, 256, 0, stream>>>(theta, thT);
  k1_A2<<<dim3(16, 16, 8), 256, 0, stream>>>(cheb, att, A2);
  k2_xT<<<dim3(64, 8), 256, 0, stream>>>(x, xT);
  k3_Y<<<dim3(4, 36, 8), 256, 0, stream>>>(xT, thT, Y);
  k4_main<<<768, 256, 0, stream>>>(A2, Y, out);
}